// Round 1
// baseline (487.935 us; speedup 1.0000x reference)
//
#include <hip/hip_runtime.h>
#include <hip/hip_bf16.h>

// MoE FFN: B=2,S=2048 -> T=4096 tokens, D=1024, E=8, H=1408, top-2.
// Strategy: router -> per-expert token lists (slot=2t+k) -> gathered bf16 MFMA
// GEMMs (gate+up fused w/ silu, then down, scaled by norm'd top2 weight) ->
// combine two slots per token. All fp32->bf16 conversion happens during LDS
// staging (RNE via compiler (__bf16) casts).

#define T_TOK 4096
#define D_DIM 1024
#define E_NUM 8
#define H_DIM 1408

#define BM 128
#define BN 128
#define BK 32
#define PAD 40  // bf16 elems per LDS row: 32 + 8 pad (80B stride, 16B-aligned b128 reads)

typedef __bf16 bf16_t;
typedef __bf16 bf16x8 __attribute__((ext_vector_type(8)));
typedef float f32x4 __attribute__((ext_vector_type(4)));

// ---- workspace layout (bytes) ----
#define OFF_COUNTS 0
#define OFF_COMB   256
#define OFF_LISTS  (OFF_COMB + T_TOK * E_NUM * 4)                 // 131328
#define OFF_H      (OFF_LISTS + E_NUM * T_TOK * 4)                // 262400 (256-aligned)
#define OFF_CONTRIB (OFF_H + 2 * T_TOK * H_DIM * 2)               // + 23068672
// total = OFF_CONTRIB + 2*T_TOK*D_DIM*2 = ~40.1 MB

__global__ void zero_counts_kernel(int* counts) {
    if (threadIdx.x < E_NUM) counts[threadIdx.x] = 0;
}

// One wave per token: logits, softmax, top-2, normalized weights, list append.
__global__ __launch_bounds__(64) void router_kernel(
    const float* __restrict__ x, const float* __restrict__ wr,
    float* __restrict__ comb, int* __restrict__ lists, int* __restrict__ counts)
{
    int t = blockIdx.x;
    int lane = threadIdx.x;
    const float* xr = x + (size_t)t * D_DIM;

    float acc[E_NUM] = {0.f, 0.f, 0.f, 0.f, 0.f, 0.f, 0.f, 0.f};
#pragma unroll
    for (int j = 0; j < D_DIM / 64; ++j) {
        float xv = xr[lane + 64 * j];
        const float* w = wr + (size_t)(lane + 64 * j) * E_NUM;
#pragma unroll
        for (int e = 0; e < E_NUM; ++e) acc[e] += xv * w[e];
    }
#pragma unroll
    for (int off = 32; off > 0; off >>= 1) {
#pragma unroll
        for (int e = 0; e < E_NUM; ++e) acc[e] += __shfl_xor(acc[e], off, 64);
    }
    if (lane == 0) {
        float m = acc[0];
#pragma unroll
        for (int e = 1; e < E_NUM; ++e) m = fmaxf(m, acc[e]);
        float ex[E_NUM], Z = 0.f;
#pragma unroll
        for (int e = 0; e < E_NUM; ++e) { ex[e] = expf(acc[e] - m); Z += ex[e]; }
        float inv = 1.f / Z;
        // top-2 (first occurrence on ties, matching lax.top_k)
        int e0 = 0; float v0 = ex[0];
#pragma unroll
        for (int e = 1; e < E_NUM; ++e) if (ex[e] > v0) { v0 = ex[e]; e0 = e; }
        int e1 = -1; float v1 = -1.f;
#pragma unroll
        for (int e = 0; e < E_NUM; ++e) if (e != e0 && ex[e] > v1) { v1 = ex[e]; e1 = e; }
        float p0 = v0 * inv, p1 = v1 * inv;
        float s = p0 + p1 + 1e-20f;
        comb[t * E_NUM + e0] = p0 / s;
        comb[t * E_NUM + e1] = p1 / s;
        int q0 = atomicAdd(&counts[e0], 1);
        lists[e0 * T_TOK + q0] = t * 2;
        int q1 = atomicAdd(&counts[e1], 1);
        lists[e1 * T_TOK + q1] = t * 2 + 1;
    }
}

// GEMM1: for expert e, rows = gathered tokens, C = [rows x H]:
//   g = X@Wg, u = X@Wu, h = silu(g)*u  (bf16 out to ws)
__global__ __launch_bounds__(256) void gemm1_kernel(
    const float* __restrict__ x, const float* __restrict__ wg,
    const float* __restrict__ wu, const int* __restrict__ lists,
    const int* __restrict__ counts, bf16_t* __restrict__ h)
{
    const int NT = H_DIM / BN;  // 11
    const int MT = T_TOK / BM;  // 32
    int bid = blockIdx.x;
    int e = bid / (MT * NT);
    int rem = bid - e * (MT * NT);
    int mt = rem / NT;
    int nt = rem - mt * NT;
    int cnt = counts[e];
    int mbase = mt * BM;
    if (mbase >= cnt) return;
    int rows = min(BM, cnt - mbase);

    __shared__ bf16_t As[BM][PAD];
    __shared__ bf16_t Bgs[BN][PAD];
    __shared__ bf16_t Bus[BN][PAD];
    __shared__ int slots[BM];

    int tid = threadIdx.x;
    if (tid < BM) slots[tid] = (tid < rows) ? lists[e * T_TOK + mbase + tid] : 0;
    __syncthreads();

    // A staging: thread -> (row ra, k-half ka), 16 floats contiguous
    int ra = tid >> 1;
    int ka = (tid & 1) * 16;
    const float* xrow = x + (size_t)(slots[ra] >> 1) * D_DIM + ka;

    // B staging: thread -> (k row kb, 16-col chunk cb), coalesced along n
    int kb = tid & 31;
    int cb = (tid >> 5) * 16;
    const float* gp = wg + ((size_t)e * D_DIM + kb) * H_DIM + (size_t)nt * BN + cb;
    const float* up = wu + ((size_t)e * D_DIM + kb) * H_DIM + (size_t)nt * BN + cb;

    int wid = tid >> 6, lane = tid & 63;
    int wm = (wid >> 1) * 64, wn = (wid & 1) * 64;
    int lr = lane & 15, lq = lane >> 4;

    f32x4 accg[4][4], accu[4][4];
#pragma unroll
    for (int i = 0; i < 4; ++i)
#pragma unroll
        for (int j = 0; j < 4; ++j) {
            accg[i][j] = (f32x4){0.f, 0.f, 0.f, 0.f};
            accu[i][j] = (f32x4){0.f, 0.f, 0.f, 0.f};
        }

    for (int kt = 0; kt < D_DIM / BK; ++kt) {
        // ---- stage A (fp32 -> bf16) ----
        {
            const float4* s4 = (const float4*)(xrow + kt * BK);
            bf16x8 lo, hi;
#pragma unroll
            for (int q = 0; q < 2; ++q) {
                float4 f = s4[q];
                lo[q * 4 + 0] = (bf16_t)f.x; lo[q * 4 + 1] = (bf16_t)f.y;
                lo[q * 4 + 2] = (bf16_t)f.z; lo[q * 4 + 3] = (bf16_t)f.w;
            }
#pragma unroll
            for (int q = 0; q < 2; ++q) {
                float4 f = s4[2 + q];
                hi[q * 4 + 0] = (bf16_t)f.x; hi[q * 4 + 1] = (bf16_t)f.y;
                hi[q * 4 + 2] = (bf16_t)f.z; hi[q * 4 + 3] = (bf16_t)f.w;
            }
            *(bf16x8*)(&As[ra][ka]) = lo;
            *(bf16x8*)(&As[ra][ka + 8]) = hi;
        }
        // ---- stage Bg / Bu (transpose-on-write, n-major LDS [n][k]) ----
        {
            const float4* s4 = (const float4*)(gp + (size_t)kt * BK * H_DIM);
#pragma unroll
            for (int q = 0; q < 4; ++q) {
                float4 f = s4[q];
                Bgs[cb + q * 4 + 0][kb] = (bf16_t)f.x;
                Bgs[cb + q * 4 + 1][kb] = (bf16_t)f.y;
                Bgs[cb + q * 4 + 2][kb] = (bf16_t)f.z;
                Bgs[cb + q * 4 + 3][kb] = (bf16_t)f.w;
            }
        }
        {
            const float4* s4 = (const float4*)(up + (size_t)kt * BK * H_DIM);
#pragma unroll
            for (int q = 0; q < 4; ++q) {
                float4 f = s4[q];
                Bus[cb + q * 4 + 0][kb] = (bf16_t)f.x;
                Bus[cb + q * 4 + 1][kb] = (bf16_t)f.y;
                Bus[cb + q * 4 + 2][kb] = (bf16_t)f.z;
                Bus[cb + q * 4 + 3][kb] = (bf16_t)f.w;
            }
        }
        __syncthreads();

        bf16x8 af[4], bg[4], bu[4];
#pragma unroll
        for (int i = 0; i < 4; ++i)
            af[i] = *(const bf16x8*)(&As[wm + i * 16 + lr][lq * 8]);
#pragma unroll
        for (int j = 0; j < 4; ++j) {
            bg[j] = *(const bf16x8*)(&Bgs[wn + j * 16 + lr][lq * 8]);
            bu[j] = *(const bf16x8*)(&Bus[wn + j * 16 + lr][lq * 8]);
        }
#pragma unroll
        for (int i = 0; i < 4; ++i)
#pragma unroll
            for (int j = 0; j < 4; ++j) {
                accg[i][j] = __builtin_amdgcn_mfma_f32_16x16x32_bf16(af[i], bg[j], accg[i][j], 0, 0, 0);
                accu[i][j] = __builtin_amdgcn_mfma_f32_16x16x32_bf16(af[i], bu[j], accu[i][j], 0, 0, 0);
            }
        __syncthreads();
    }

    // epilogue: h = silu(g)*u
#pragma unroll
    for (int i = 0; i < 4; ++i) {
#pragma unroll
        for (int jj = 0; jj < 4; ++jj) {
            int row = wm + i * 16 + lq * 4 + jj;
            if (row < rows) {
                int slot = slots[row];
                bf16_t* hrow = h + (size_t)slot * H_DIM + (size_t)nt * BN + wn;
#pragma unroll
                for (int j = 0; j < 4; ++j) {
                    float g = accg[i][j][jj];
                    float u = accu[i][j][jj];
                    float val = (g / (1.f + __expf(-g))) * u;
                    hrow[j * 16 + lr] = (bf16_t)val;
                }
            }
        }
    }
}

// GEMM2: C = h @ Wd[e], scaled per-row by comb weight -> contrib[slot][D] bf16
__global__ __launch_bounds__(256) void gemm2_kernel(
    const bf16_t* __restrict__ h, const float* __restrict__ wd,
    const int* __restrict__ lists, const int* __restrict__ counts,
    const float* __restrict__ comb, bf16_t* __restrict__ contrib)
{
    const int NT = D_DIM / BN;  // 8
    const int MT = T_TOK / BM;  // 32
    int bid = blockIdx.x;
    int e = bid / (MT * NT);
    int rem = bid - e * (MT * NT);
    int mt = rem / NT;
    int nt = rem - mt * NT;
    int cnt = counts[e];
    int mbase = mt * BM;
    if (mbase >= cnt) return;
    int rows = min(BM, cnt - mbase);

    __shared__ bf16_t As[BM][PAD];
    __shared__ bf16_t Bs[BN][PAD];
    __shared__ int slots[BM];

    int tid = threadIdx.x;
    if (tid < BM) slots[tid] = (tid < rows) ? lists[e * T_TOK + mbase + tid] : 0;
    __syncthreads();

    int ra = tid >> 1;
    int ka = (tid & 1) * 16;
    const bf16_t* hrow = h + (size_t)slots[ra] * H_DIM + ka;

    int kb = tid & 31;
    int cb = (tid >> 5) * 16;
    const float* dp = wd + ((size_t)e * H_DIM + kb) * D_DIM + (size_t)nt * BN + cb;

    int wid = tid >> 6, lane = tid & 63;
    int wm = (wid >> 1) * 64, wn = (wid & 1) * 64;
    int lr = lane & 15, lq = lane >> 4;

    f32x4 acc[4][4];
#pragma unroll
    for (int i = 0; i < 4; ++i)
#pragma unroll
        for (int j = 0; j < 4; ++j) acc[i][j] = (f32x4){0.f, 0.f, 0.f, 0.f};

    for (int kt = 0; kt < H_DIM / BK; ++kt) {
        // A: already bf16, plain 32B copy per thread
        {
            const uint4* s = (const uint4*)(hrow + (size_t)kt * BK);
            uint4 v0 = s[0], v1 = s[1];
            *(uint4*)(&As[ra][ka]) = v0;
            *(uint4*)(&As[ra][ka + 8]) = v1;
        }
        // B: transpose-on-write
        {
            const float4* s4 = (const float4*)(dp + (size_t)kt * BK * D_DIM);
#pragma unroll
            for (int q = 0; q < 4; ++q) {
                float4 f = s4[q];
                Bs[cb + q * 4 + 0][kb] = (bf16_t)f.x;
                Bs[cb + q * 4 + 1][kb] = (bf16_t)f.y;
                Bs[cb + q * 4 + 2][kb] = (bf16_t)f.z;
                Bs[cb + q * 4 + 3][kb] = (bf16_t)f.w;
            }
        }
        __syncthreads();

        bf16x8 af[4], bf[4];
#pragma unroll
        for (int i = 0; i < 4; ++i)
            af[i] = *(const bf16x8*)(&As[wm + i * 16 + lr][lq * 8]);
#pragma unroll
        for (int j = 0; j < 4; ++j)
            bf[j] = *(const bf16x8*)(&Bs[wn + j * 16 + lr][lq * 8]);
#pragma unroll
        for (int i = 0; i < 4; ++i)
#pragma unroll
            for (int j = 0; j < 4; ++j)
                acc[i][j] = __builtin_amdgcn_mfma_f32_16x16x32_bf16(af[i], bf[j], acc[i][j], 0, 0, 0);
        __syncthreads();
    }

#pragma unroll
    for (int i = 0; i < 4; ++i) {
#pragma unroll
        for (int jj = 0; jj < 4; ++jj) {
            int row = wm + i * 16 + lq * 4 + jj;
            if (row < rows) {
                int slot = slots[row];
                float wgt = comb[(slot >> 1) * E_NUM + e];
                bf16_t* crow = contrib + (size_t)slot * D_DIM + (size_t)nt * BN + wn;
#pragma unroll
                for (int j = 0; j < 4; ++j)
                    crow[j * 16 + lr] = (bf16_t)(acc[i][j][jj] * wgt);
            }
        }
    }
}

// out[t][d] = contrib[2t][d] + contrib[2t+1][d]
__global__ __launch_bounds__(256) void combine_kernel(
    const bf16_t* __restrict__ contrib, float* __restrict__ out)
{
    int idx = blockIdx.x * 256 + threadIdx.x;  // octet index, T*D/8 total
    int t = idx >> 7;                          // D/8 = 128 octets per row
    int d = (idx & 127) * 8;
    bf16x8 a = *(const bf16x8*)(contrib + (size_t)(2 * t) * D_DIM + d);
    bf16x8 b = *(const bf16x8*)(contrib + (size_t)(2 * t + 1) * D_DIM + d);
    float4 r0, r1;
    r0.x = (float)a[0] + (float)b[0];
    r0.y = (float)a[1] + (float)b[1];
    r0.z = (float)a[2] + (float)b[2];
    r0.w = (float)a[3] + (float)b[3];
    r1.x = (float)a[4] + (float)b[4];
    r1.y = (float)a[5] + (float)b[5];
    r1.z = (float)a[6] + (float)b[6];
    r1.w = (float)a[7] + (float)b[7];
    *(float4*)(out + (size_t)t * D_DIM + d) = r0;
    *(float4*)(out + (size_t)t * D_DIM + d + 4) = r1;
}

extern "C" void kernel_launch(void* const* d_in, const int* in_sizes, int n_in,
                              void* d_out, int out_size, void* d_ws, size_t ws_size,
                              hipStream_t stream)
{
    const float* x  = (const float*)d_in[0];
    const float* wr = (const float*)d_in[1];
    const float* wg = (const float*)d_in[2];
    const float* wu = (const float*)d_in[3];
    const float* wd = (const float*)d_in[4];
    float* out = (float*)d_out;

    char* ws = (char*)d_ws;
    int*    counts  = (int*)(ws + OFF_COUNTS);
    float*  comb    = (float*)(ws + OFF_COMB);
    int*    lists   = (int*)(ws + OFF_LISTS);
    bf16_t* h       = (bf16_t*)(ws + OFF_H);
    bf16_t* contrib = (bf16_t*)(ws + OFF_CONTRIB);

    zero_counts_kernel<<<dim3(1), dim3(64), 0, stream>>>(counts);
    router_kernel<<<dim3(T_TOK), dim3(64), 0, stream>>>(x, wr, comb, lists, counts);
    gemm1_kernel<<<dim3(E_NUM * (T_TOK / BM) * (H_DIM / BN)), dim3(256), 0, stream>>>(
        x, wg, wu, lists, counts, h);
    gemm2_kernel<<<dim3(E_NUM * (T_TOK / BM) * (D_DIM / BN)), dim3(256), 0, stream>>>(
        h, wd, lists, counts, comb, contrib);
    combine_kernel<<<dim3(T_TOK * D_DIM / 8 / 256), dim3(256), 0, stream>>>(contrib, out);
}

// Round 2
// 307.002 us; speedup vs baseline: 1.5894x; 1.5894x over previous
//
#include <hip/hip_runtime.h>
#include <hip/hip_bf16.h>

// MoE FFN: T=4096 tokens, D=1024, E=8, H=1408, top-2.
// R2: pre-convert/transpose weights to bf16 ([E][H][D] for gate/up, [E][D][H]
// for down), x->bf16 in router, then m97-class MFMA GEMMs with
// global_load_lds(16B) staging and linear LDS tiles.

#define T_TOK 4096
#define D_DIM 1024
#define E_NUM 8
#define H_DIM 1408

typedef __bf16 bf16_t;
typedef __bf16 bf16x8 __attribute__((ext_vector_type(8)));
typedef float f32x4 __attribute__((ext_vector_type(4)));

// ---- workspace layout (bytes) ----
#define OFF_COUNTS   0
#define OFF_COMB     256                                  // T*E*4 = 131072
#define OFF_LISTS    (OFF_COMB + T_TOK*E_NUM*4)
#define OFF_XBF      (OFF_LISTS + E_NUM*T_TOK*4)          // T*D*2 = 8388608
#define OFF_WGT      (OFF_XBF + (size_t)T_TOK*D_DIM*2)    // E*H*D*2 = 23068672
#define OFF_WUT      (OFF_WGT + (size_t)E_NUM*H_DIM*D_DIM*2)
#define OFF_WDT      (OFF_WUT + (size_t)E_NUM*H_DIM*D_DIM*2)
#define OFF_H        (OFF_WDT + (size_t)E_NUM*H_DIM*D_DIM*2)
#define OFF_CONTRIB  (OFF_H + (size_t)2*T_TOK*H_DIM*2)
// total ~117.7 MB

__device__ __forceinline__ void gload16(const bf16_t* g, bf16_t* l) {
    __builtin_amdgcn_global_load_lds(
        (const __attribute__((address_space(1))) void*)g,
        (__attribute__((address_space(3))) void*)l,
        16, 0, 0);
}

__global__ void zero_counts_kernel(int* counts) {
    if (threadIdx.x < E_NUM) counts[threadIdx.x] = 0;
}

// Tiled transpose+convert: per expert, in [R][C] fp32 -> out [C][R] bf16.
__global__ __launch_bounds__(256) void transpose_cvt_kernel(
    const float* __restrict__ in, bf16_t* __restrict__ out, int R, int C)
{
    int e = blockIdx.z;
    int rt = blockIdx.y, ct = blockIdx.x;
    __shared__ bf16_t tile[64][65];
    int tid = threadIdx.x;
    int r = tid >> 2, c0 = (tid & 3) * 16;
    const float* src = in + ((size_t)e * R + rt * 64) * C + (size_t)ct * 64;
#pragma unroll
    for (int q = 0; q < 4; ++q) {
        float4 f = *(const float4*)(src + (size_t)r * C + c0 + q * 4);
        tile[c0 + q * 4 + 0][r] = (bf16_t)f.x;
        tile[c0 + q * 4 + 1][r] = (bf16_t)f.y;
        tile[c0 + q * 4 + 2][r] = (bf16_t)f.z;
        tile[c0 + q * 4 + 3][r] = (bf16_t)f.w;
    }
    __syncthreads();
    bf16_t* dst = out + ((size_t)e * C + ct * 64) * R + (size_t)rt * 64;
    int cc = tid >> 2, rr0 = (tid & 3) * 16;
    bf16x8 v0, v1;
#pragma unroll
    for (int q = 0; q < 8; ++q) { v0[q] = tile[cc][rr0 + q]; v1[q] = tile[cc][rr0 + 8 + q]; }
    *(bf16x8*)(dst + (size_t)cc * R + rr0) = v0;
    *(bf16x8*)(dst + (size_t)cc * R + rr0 + 8) = v1;
}

// One wave per token: logits, softmax, top-2, list append; also x -> bf16.
__global__ __launch_bounds__(64) void router_kernel(
    const float* __restrict__ x, const float* __restrict__ wr,
    bf16_t* __restrict__ xbf, float* __restrict__ comb,
    int* __restrict__ lists, int* __restrict__ counts)
{
    int t = blockIdx.x;
    int lane = threadIdx.x;
    const float* xr = x + (size_t)t * D_DIM;

    // bf16 convert: lane owns 16 contiguous floats
    {
        const float4* xv4 = (const float4*)(xr + lane * 16);
        bf16_t* xbr = xbf + (size_t)t * D_DIM + lane * 16;
        float4 f0 = xv4[0], f1 = xv4[1], f2 = xv4[2], f3 = xv4[3];
        bf16x8 v0, v1;
        v0[0] = (bf16_t)f0.x; v0[1] = (bf16_t)f0.y; v0[2] = (bf16_t)f0.z; v0[3] = (bf16_t)f0.w;
        v0[4] = (bf16_t)f1.x; v0[5] = (bf16_t)f1.y; v0[6] = (bf16_t)f1.z; v0[7] = (bf16_t)f1.w;
        v1[0] = (bf16_t)f2.x; v1[1] = (bf16_t)f2.y; v1[2] = (bf16_t)f2.z; v1[3] = (bf16_t)f2.w;
        v1[4] = (bf16_t)f3.x; v1[5] = (bf16_t)f3.y; v1[6] = (bf16_t)f3.z; v1[7] = (bf16_t)f3.w;
        *(bf16x8*)(xbr) = v0;
        *(bf16x8*)(xbr + 8) = v1;
    }

    float acc[E_NUM] = {0.f, 0.f, 0.f, 0.f, 0.f, 0.f, 0.f, 0.f};
#pragma unroll
    for (int j = 0; j < D_DIM / 64; ++j) {
        float xv = xr[lane + 64 * j];
        const float* w = wr + (size_t)(lane + 64 * j) * E_NUM;
#pragma unroll
        for (int e = 0; e < E_NUM; ++e) acc[e] += xv * w[e];
    }
#pragma unroll
    for (int off = 32; off > 0; off >>= 1) {
#pragma unroll
        for (int e = 0; e < E_NUM; ++e) acc[e] += __shfl_xor(acc[e], off, 64);
    }
    if (lane == 0) {
        float m = acc[0];
#pragma unroll
        for (int e = 1; e < E_NUM; ++e) m = fmaxf(m, acc[e]);
        float ex[E_NUM], Z = 0.f;
#pragma unroll
        for (int e = 0; e < E_NUM; ++e) { ex[e] = expf(acc[e] - m); Z += ex[e]; }
        float inv = 1.f / Z;
        int e0 = 0; float v0 = ex[0];
#pragma unroll
        for (int e = 1; e < E_NUM; ++e) if (ex[e] > v0) { v0 = ex[e]; e0 = e; }
        int e1 = -1; float v1 = -1.f;
#pragma unroll
        for (int e = 0; e < E_NUM; ++e) if (e != e0 && ex[e] > v1) { v1 = ex[e]; e1 = e; }
        float p0 = v0 * inv, p1 = v1 * inv;
        float s = p0 + p1 + 1e-20f;
        comb[t * E_NUM + e0] = p0 / s;
        comb[t * E_NUM + e1] = p1 / s;
        int q0 = atomicAdd(&counts[e0], 1);
        lists[e0 * T_TOK + q0] = t * 2;
        int q1 = atomicAdd(&counts[e1], 1);
        lists[e1 * T_TOK + q1] = t * 2 + 1;
    }
}

// GEMM1: h[slot] = silu(x@Wg) * (x@Wu) for expert-gathered rows. 128x128 tile,
// BK=32, 4 waves x (64x64), global_load_lds staging, linear LDS.
__global__ __launch_bounds__(256, 2) void gemm1_kernel(
    const bf16_t* __restrict__ xbf, const bf16_t* __restrict__ wgT,
    const bf16_t* __restrict__ wuT, const int* __restrict__ lists,
    const int* __restrict__ counts, bf16_t* __restrict__ h)
{
    const int NT = H_DIM / 128;  // 11
    const int MT = T_TOK / 128;  // 32
    int bid = blockIdx.x;
    int e = bid / (MT * NT);
    int rem = bid - e * (MT * NT);
    int mt = rem / NT;
    int nt = rem - mt * NT;
    int cnt = counts[e];
    int mbase = mt * 128;
    if (mbase >= cnt) return;
    int rows = min(128, cnt - mbase);

    __shared__ __align__(16) bf16_t As[128 * 32];
    __shared__ __align__(16) bf16_t Bg[128 * 32];
    __shared__ __align__(16) bf16_t Bu[128 * 32];
    __shared__ int slots[128];

    int tid = threadIdx.x;
    if (tid < 128) slots[tid] = (tid < rows) ? lists[e * T_TOK + mbase + tid] : 0;
    __syncthreads();

    int r0 = tid >> 2;          // 0..63
    int c0 = (tid & 3) * 8;     // bf16 col within 32
    const bf16_t* gA0 = xbf + (size_t)(slots[r0] >> 1) * D_DIM + c0;
    const bf16_t* gA1 = xbf + (size_t)(slots[64 + r0] >> 1) * D_DIM + c0;
    const bf16_t* gB0 = wgT + ((size_t)e * H_DIM + nt * 128 + r0) * D_DIM + c0;
    const bf16_t* gB1 = gB0 + (size_t)64 * D_DIM;
    const bf16_t* gU0 = wuT + ((size_t)e * H_DIM + nt * 128 + r0) * D_DIM + c0;
    const bf16_t* gU1 = gU0 + (size_t)64 * D_DIM;
    bf16_t* lA = As + tid * 8;
    bf16_t* lBg = Bg + tid * 8;
    bf16_t* lBu = Bu + tid * 8;

    int wid = tid >> 6, lane = tid & 63;
    int wm = (wid >> 1) * 64, wn = (wid & 1) * 64;
    int lr = lane & 15, lq = lane >> 4;

    f32x4 accg[4][4], accu[4][4];
#pragma unroll
    for (int i = 0; i < 4; ++i)
#pragma unroll
        for (int j = 0; j < 4; ++j) {
            accg[i][j] = (f32x4){0.f, 0.f, 0.f, 0.f};
            accu[i][j] = (f32x4){0.f, 0.f, 0.f, 0.f};
        }

    for (int kt = 0; kt < D_DIM; kt += 32) {
        gload16(gA0 + kt, lA);
        gload16(gA1 + kt, lA + 2048);
        gload16(gB0 + kt, lBg);
        gload16(gB1 + kt, lBg + 2048);
        gload16(gU0 + kt, lBu);
        gload16(gU1 + kt, lBu + 2048);
        __syncthreads();

        bf16x8 af[4], bg[4], bu[4];
#pragma unroll
        for (int i = 0; i < 4; ++i)
            af[i] = *(const bf16x8*)(As + (wm + i * 16 + lr) * 32 + lq * 8);
#pragma unroll
        for (int j = 0; j < 4; ++j) {
            bg[j] = *(const bf16x8*)(Bg + (wn + j * 16 + lr) * 32 + lq * 8);
            bu[j] = *(const bf16x8*)(Bu + (wn + j * 16 + lr) * 32 + lq * 8);
        }
#pragma unroll
        for (int i = 0; i < 4; ++i)
#pragma unroll
            for (int j = 0; j < 4; ++j) {
                accg[i][j] = __builtin_amdgcn_mfma_f32_16x16x32_bf16(af[i], bg[j], accg[i][j], 0, 0, 0);
                accu[i][j] = __builtin_amdgcn_mfma_f32_16x16x32_bf16(af[i], bu[j], accu[i][j], 0, 0, 0);
            }
        __syncthreads();
    }

#pragma unroll
    for (int i = 0; i < 4; ++i) {
#pragma unroll
        for (int jj = 0; jj < 4; ++jj) {
            int row = wm + i * 16 + lq * 4 + jj;
            if (row < rows) {
                int slot = slots[row];
                bf16_t* hrow = h + (size_t)slot * H_DIM + (size_t)nt * 128 + wn;
#pragma unroll
                for (int j = 0; j < 4; ++j) {
                    float g = accg[i][j][jj];
                    float u = accu[i][j][jj];
                    float val = (g / (1.f + __expf(-g))) * u;
                    hrow[j * 16 + lr] = (bf16_t)val;
                }
            }
        }
    }
}

// GEMM2: contrib[slot] = (h[slot] @ Wd[e]) * comb_weight
__global__ __launch_bounds__(256, 2) void gemm2_kernel(
    const bf16_t* __restrict__ h, const bf16_t* __restrict__ wdT,
    const int* __restrict__ lists, const int* __restrict__ counts,
    const float* __restrict__ comb, bf16_t* __restrict__ contrib)
{
    const int NT = D_DIM / 128;  // 8
    const int MT = T_TOK / 128;  // 32
    int bid = blockIdx.x;
    int e = bid / (MT * NT);
    int rem = bid - e * (MT * NT);
    int mt = rem / NT;
    int nt = rem - mt * NT;
    int cnt = counts[e];
    int mbase = mt * 128;
    if (mbase >= cnt) return;
    int rows = min(128, cnt - mbase);

    __shared__ __align__(16) bf16_t As[128 * 32];
    __shared__ __align__(16) bf16_t Bs[128 * 32];
    __shared__ int slots[128];

    int tid = threadIdx.x;
    if (tid < 128) slots[tid] = (tid < rows) ? lists[e * T_TOK + mbase + tid] : 0;
    __syncthreads();

    int r0 = tid >> 2;
    int c0 = (tid & 3) * 8;
    const bf16_t* gA0 = h + (size_t)slots[r0] * H_DIM + c0;
    const bf16_t* gA1 = h + (size_t)slots[64 + r0] * H_DIM + c0;
    const bf16_t* gB0 = wdT + ((size_t)e * D_DIM + nt * 128 + r0) * H_DIM + c0;
    const bf16_t* gB1 = gB0 + (size_t)64 * H_DIM;
    bf16_t* lA = As + tid * 8;
    bf16_t* lB = Bs + tid * 8;

    int wid = tid >> 6, lane = tid & 63;
    int wm = (wid >> 1) * 64, wn = (wid & 1) * 64;
    int lr = lane & 15, lq = lane >> 4;

    f32x4 acc[4][4];
#pragma unroll
    for (int i = 0; i < 4; ++i)
#pragma unroll
        for (int j = 0; j < 4; ++j) acc[i][j] = (f32x4){0.f, 0.f, 0.f, 0.f};

    for (int kt = 0; kt < H_DIM; kt += 32) {
        gload16(gA0 + kt, lA);
        gload16(gA1 + kt, lA + 2048);
        gload16(gB0 + kt, lB);
        gload16(gB1 + kt, lB + 2048);
        __syncthreads();

        bf16x8 af[4], bf[4];
#pragma unroll
        for (int i = 0; i < 4; ++i)
            af[i] = *(const bf16x8*)(As + (wm + i * 16 + lr) * 32 + lq * 8);
#pragma unroll
        for (int j = 0; j < 4; ++j)
            bf[j] = *(const bf16x8*)(Bs + (wn + j * 16 + lr) * 32 + lq * 8);
#pragma unroll
        for (int i = 0; i < 4; ++i)
#pragma unroll
            for (int j = 0; j < 4; ++j)
                acc[i][j] = __builtin_amdgcn_mfma_f32_16x16x32_bf16(af[i], bf[j], acc[i][j], 0, 0, 0);
        __syncthreads();
    }

#pragma unroll
    for (int i = 0; i < 4; ++i) {
#pragma unroll
        for (int jj = 0; jj < 4; ++jj) {
            int row = wm + i * 16 + lq * 4 + jj;
            if (row < rows) {
                int slot = slots[row];
                float wgt = comb[(slot >> 1) * E_NUM + e];
                bf16_t* crow = contrib + (size_t)slot * D_DIM + (size_t)nt * 128 + wn;
#pragma unroll
                for (int j = 0; j < 4; ++j)
                    crow[j * 16 + lr] = (bf16_t)(acc[i][j][jj] * wgt);
            }
        }
    }
}

// out[t][d] = contrib[2t][d] + contrib[2t+1][d]
__global__ __launch_bounds__(256) void combine_kernel(
    const bf16_t* __restrict__ contrib, float* __restrict__ out)
{
    int idx = blockIdx.x * 256 + threadIdx.x;
    int t = idx >> 7;
    int d = (idx & 127) * 8;
    bf16x8 a = *(const bf16x8*)(contrib + (size_t)(2 * t) * D_DIM + d);
    bf16x8 b = *(const bf16x8*)(contrib + (size_t)(2 * t + 1) * D_DIM + d);
    float4 r0, r1;
    r0.x = (float)a[0] + (float)b[0];
    r0.y = (float)a[1] + (float)b[1];
    r0.z = (float)a[2] + (float)b[2];
    r0.w = (float)a[3] + (float)b[3];
    r1.x = (float)a[4] + (float)b[4];
    r1.y = (float)a[5] + (float)b[5];
    r1.z = (float)a[6] + (float)b[6];
    r1.w = (float)a[7] + (float)b[7];
    *(float4*)(out + (size_t)t * D_DIM + d) = r0;
    *(float4*)(out + (size_t)t * D_DIM + d + 4) = r1;
}

extern "C" void kernel_launch(void* const* d_in, const int* in_sizes, int n_in,
                              void* d_out, int out_size, void* d_ws, size_t ws_size,
                              hipStream_t stream)
{
    const float* x  = (const float*)d_in[0];
    const float* wr = (const float*)d_in[1];
    const float* wg = (const float*)d_in[2];
    const float* wu = (const float*)d_in[3];
    const float* wd = (const float*)d_in[4];
    float* out = (float*)d_out;

    char* ws = (char*)d_ws;
    int*    counts  = (int*)(ws + OFF_COUNTS);
    float*  comb    = (float*)(ws + OFF_COMB);
    int*    lists   = (int*)(ws + OFF_LISTS);
    bf16_t* xbf     = (bf16_t*)(ws + OFF_XBF);
    bf16_t* wgT     = (bf16_t*)(ws + OFF_WGT);
    bf16_t* wuT     = (bf16_t*)(ws + OFF_WUT);
    bf16_t* wdT     = (bf16_t*)(ws + OFF_WDT);
    bf16_t* h       = (bf16_t*)(ws + OFF_H);
    bf16_t* contrib = (bf16_t*)(ws + OFF_CONTRIB);

    zero_counts_kernel<<<dim3(1), dim3(64), 0, stream>>>(counts);
    // wg, wu: [E][D][H] -> [E][H][D] bf16
    transpose_cvt_kernel<<<dim3(H_DIM / 64, D_DIM / 64, E_NUM), dim3(256), 0, stream>>>(
        wg, wgT, D_DIM, H_DIM);
    transpose_cvt_kernel<<<dim3(H_DIM / 64, D_DIM / 64, E_NUM), dim3(256), 0, stream>>>(
        wu, wuT, D_DIM, H_DIM);
    // wd: [E][H][D] -> [E][D][H] bf16
    transpose_cvt_kernel<<<dim3(D_DIM / 64, H_DIM / 64, E_NUM), dim3(256), 0, stream>>>(
        wd, wdT, H_DIM, D_DIM);
    router_kernel<<<dim3(T_TOK), dim3(64), 0, stream>>>(x, wr, xbf, comb, lists, counts);
    gemm1_kernel<<<dim3(E_NUM * (T_TOK / 128) * (H_DIM / 128)), dim3(256), 0, stream>>>(
        xbf, wgT, wuT, lists, counts, h);
    gemm2_kernel<<<dim3(E_NUM * (T_TOK / 128) * (D_DIM / 128)), dim3(256), 0, stream>>>(
        h, wdT, lists, counts, comb, contrib);
    combine_kernel<<<dim3(T_TOK * D_DIM / 8 / 256), dim3(256), 0, stream>>>(contrib, out);
}

// Round 3
// 218.837 us; speedup vs baseline: 2.2297x; 1.4029x over previous
//
#include <hip/hip_runtime.h>
#include <hip/hip_bf16.h>

// MoE FFN: T=4096 tokens, D=1024, E=8, H=1408, top-2.
// R3: router split into atomic-free score pass (4 waves/block) + per-expert
// compaction pass (LDS scan). GEMMs unchanged from R2 (m97-class MFMA,
// global_load_lds staging).

#define T_TOK 4096
#define D_DIM 1024
#define E_NUM 8
#define H_DIM 1408

typedef __bf16 bf16_t;
typedef __bf16 bf16x8 __attribute__((ext_vector_type(8)));
typedef float f32x4 __attribute__((ext_vector_type(4)));

// ---- workspace layout (bytes) ----
#define OFF_COUNTS   0
#define OFF_COMB     256                                   // T*E*4 = 131072
#define OFF_LISTS    (OFF_COMB + T_TOK*E_NUM*4)            // E*T*4 = 131072
#define OFF_PAIRS    (OFF_LISTS + E_NUM*T_TOK*4)           // T bytes
#define OFF_XBF      (OFF_PAIRS + T_TOK)                   // T*D*2
#define OFF_WGT      (OFF_XBF + (size_t)T_TOK*D_DIM*2)     // E*H*D*2 each
#define OFF_WUT      (OFF_WGT + (size_t)E_NUM*H_DIM*D_DIM*2)
#define OFF_WDT      (OFF_WUT + (size_t)E_NUM*H_DIM*D_DIM*2)
#define OFF_H        (OFF_WDT + (size_t)E_NUM*H_DIM*D_DIM*2)
#define OFF_CONTRIB  (OFF_H + (size_t)2*T_TOK*H_DIM*2)
// total ~117.7 MB

__device__ __forceinline__ void gload16(const bf16_t* g, bf16_t* l) {
    __builtin_amdgcn_global_load_lds(
        (const __attribute__((address_space(1))) void*)g,
        (__attribute__((address_space(3))) void*)l,
        16, 0, 0);
}

// Tiled transpose+convert: per expert, in [R][C] fp32 -> out [C][R] bf16.
__global__ __launch_bounds__(256) void transpose_cvt_kernel(
    const float* __restrict__ in, bf16_t* __restrict__ out, int R, int C)
{
    int e = blockIdx.z;
    int rt = blockIdx.y, ct = blockIdx.x;
    __shared__ bf16_t tile[64][65];
    int tid = threadIdx.x;
    int r = tid >> 2, c0 = (tid & 3) * 16;
    const float* src = in + ((size_t)e * R + rt * 64) * C + (size_t)ct * 64;
#pragma unroll
    for (int q = 0; q < 4; ++q) {
        float4 f = *(const float4*)(src + (size_t)r * C + c0 + q * 4);
        tile[c0 + q * 4 + 0][r] = (bf16_t)f.x;
        tile[c0 + q * 4 + 1][r] = (bf16_t)f.y;
        tile[c0 + q * 4 + 2][r] = (bf16_t)f.z;
        tile[c0 + q * 4 + 3][r] = (bf16_t)f.w;
    }
    __syncthreads();
    bf16_t* dst = out + ((size_t)e * C + ct * 64) * R + (size_t)rt * 64;
    int cc = tid >> 2, rr0 = (tid & 3) * 16;
    bf16x8 v0, v1;
#pragma unroll
    for (int q = 0; q < 8; ++q) { v0[q] = tile[cc][rr0 + q]; v1[q] = tile[cc][rr0 + 8 + q]; }
    *(bf16x8*)(dst + (size_t)cc * R + rr0) = v0;
    *(bf16x8*)(dst + (size_t)cc * R + rr0 + 8) = v1;
}

// Phase A: 4 waves/block, one token per wave. Logits, softmax, top-2.
// Writes comb weights + packed expert pair. No atomics. Also x -> bf16.
__global__ __launch_bounds__(256) void router_score_kernel(
    const float* __restrict__ x, const float* __restrict__ wr,
    bf16_t* __restrict__ xbf, float* __restrict__ comb,
    unsigned char* __restrict__ pairs)
{
    int widx = threadIdx.x >> 6;
    int lane = threadIdx.x & 63;
    int t = blockIdx.x * 4 + widx;
    const float* xr = x + (size_t)t * D_DIM;

    // bf16 convert: lane owns 16 contiguous floats
    {
        const float4* xv4 = (const float4*)(xr + lane * 16);
        bf16_t* xbr = xbf + (size_t)t * D_DIM + lane * 16;
        float4 f0 = xv4[0], f1 = xv4[1], f2 = xv4[2], f3 = xv4[3];
        bf16x8 v0, v1;
        v0[0] = (bf16_t)f0.x; v0[1] = (bf16_t)f0.y; v0[2] = (bf16_t)f0.z; v0[3] = (bf16_t)f0.w;
        v0[4] = (bf16_t)f1.x; v0[5] = (bf16_t)f1.y; v0[6] = (bf16_t)f1.z; v0[7] = (bf16_t)f1.w;
        v1[0] = (bf16_t)f2.x; v1[1] = (bf16_t)f2.y; v1[2] = (bf16_t)f2.z; v1[3] = (bf16_t)f2.w;
        v1[4] = (bf16_t)f3.x; v1[5] = (bf16_t)f3.y; v1[6] = (bf16_t)f3.z; v1[7] = (bf16_t)f3.w;
        *(bf16x8*)(xbr) = v0;
        *(bf16x8*)(xbr + 8) = v1;
    }

    float acc[E_NUM] = {0.f, 0.f, 0.f, 0.f, 0.f, 0.f, 0.f, 0.f};
#pragma unroll
    for (int j = 0; j < D_DIM / 64; ++j) {
        float xv = xr[lane + 64 * j];
        const float* w = wr + (size_t)(lane + 64 * j) * E_NUM;
#pragma unroll
        for (int e = 0; e < E_NUM; ++e) acc[e] += xv * w[e];
    }
#pragma unroll
    for (int off = 32; off > 0; off >>= 1) {
#pragma unroll
        for (int e = 0; e < E_NUM; ++e) acc[e] += __shfl_xor(acc[e], off, 64);
    }
    if (lane == 0) {
        float m = acc[0];
#pragma unroll
        for (int e = 1; e < E_NUM; ++e) m = fmaxf(m, acc[e]);
        float ex[E_NUM], Z = 0.f;
#pragma unroll
        for (int e = 0; e < E_NUM; ++e) { ex[e] = expf(acc[e] - m); Z += ex[e]; }
        float inv = 1.f / Z;
        int e0 = 0; float v0 = ex[0];
#pragma unroll
        for (int e = 1; e < E_NUM; ++e) if (ex[e] > v0) { v0 = ex[e]; e0 = e; }
        int e1 = -1; float v1 = -1.f;
#pragma unroll
        for (int e = 0; e < E_NUM; ++e) if (e != e0 && ex[e] > v1) { v1 = ex[e]; e1 = e; }
        float p0 = v0 * inv, p1 = v1 * inv;
        float s = p0 + p1 + 1e-20f;
        comb[t * E_NUM + e0] = p0 / s;
        comb[t * E_NUM + e1] = p1 / s;
        pairs[t] = (unsigned char)(e0 | (e1 << 4));
    }
}

// Phase B: one block per expert. Compact matching slots via LDS scan.
// Deterministic (token order), no atomics.
__global__ __launch_bounds__(256) void build_lists_kernel(
    const unsigned char* __restrict__ pairs, int* __restrict__ lists,
    int* __restrict__ counts)
{
    int e = blockIdx.x;
    int tid = threadIdx.x;
    __shared__ int cnt[256];

    const int TPT = T_TOK / 256;  // 16 tokens per thread
    int n = 0;
#pragma unroll
    for (int q = 0; q < TPT; ++q) {
        int p = pairs[tid * TPT + q];
        if ((p & 15) == e || (p >> 4) == e) ++n;
    }
    cnt[tid] = n;
    __syncthreads();
    // Hillis-Steele inclusive scan
#pragma unroll
    for (int off = 1; off < 256; off <<= 1) {
        int v = (tid >= off) ? cnt[tid - off] : 0;
        __syncthreads();
        cnt[tid] += v;
        __syncthreads();
    }
    int base = cnt[tid] - n;
    if (tid == 255) counts[e] = cnt[255];
    int* dst = lists + e * T_TOK;
#pragma unroll
    for (int q = 0; q < TPT; ++q) {
        int t = tid * TPT + q;
        int p = pairs[t];
        if ((p & 15) == e)      dst[base++] = 2 * t;
        else if ((p >> 4) == e) dst[base++] = 2 * t + 1;
    }
}

// GEMM1: h[slot] = silu(x@Wg) * (x@Wu) for expert-gathered rows. 128x128 tile,
// BK=32, 4 waves x (64x64), global_load_lds staging, linear LDS.
__global__ __launch_bounds__(256, 2) void gemm1_kernel(
    const bf16_t* __restrict__ xbf, const bf16_t* __restrict__ wgT,
    const bf16_t* __restrict__ wuT, const int* __restrict__ lists,
    const int* __restrict__ counts, bf16_t* __restrict__ h)
{
    const int NT = H_DIM / 128;  // 11
    const int MT = T_TOK / 128;  // 32
    int bid = blockIdx.x;
    int e = bid / (MT * NT);
    int rem = bid - e * (MT * NT);
    int mt = rem / NT;
    int nt = rem - mt * NT;
    int cnt = counts[e];
    int mbase = mt * 128;
    if (mbase >= cnt) return;
    int rows = min(128, cnt - mbase);

    __shared__ __align__(16) bf16_t As[128 * 32];
    __shared__ __align__(16) bf16_t Bg[128 * 32];
    __shared__ __align__(16) bf16_t Bu[128 * 32];
    __shared__ int slots[128];

    int tid = threadIdx.x;
    if (tid < 128) slots[tid] = (tid < rows) ? lists[e * T_TOK + mbase + tid] : 0;
    __syncthreads();

    int r0 = tid >> 2;          // 0..63
    int c0 = (tid & 3) * 8;     // bf16 col within 32
    const bf16_t* gA0 = xbf + (size_t)(slots[r0] >> 1) * D_DIM + c0;
    const bf16_t* gA1 = xbf + (size_t)(slots[64 + r0] >> 1) * D_DIM + c0;
    const bf16_t* gB0 = wgT + ((size_t)e * H_DIM + nt * 128 + r0) * D_DIM + c0;
    const bf16_t* gB1 = gB0 + (size_t)64 * D_DIM;
    const bf16_t* gU0 = wuT + ((size_t)e * H_DIM + nt * 128 + r0) * D_DIM + c0;
    const bf16_t* gU1 = gU0 + (size_t)64 * D_DIM;
    bf16_t* lA = As + tid * 8;
    bf16_t* lBg = Bg + tid * 8;
    bf16_t* lBu = Bu + tid * 8;

    int wid = tid >> 6, lane = tid & 63;
    int wm = (wid >> 1) * 64, wn = (wid & 1) * 64;
    int lr = lane & 15, lq = lane >> 4;

    f32x4 accg[4][4], accu[4][4];
#pragma unroll
    for (int i = 0; i < 4; ++i)
#pragma unroll
        for (int j = 0; j < 4; ++j) {
            accg[i][j] = (f32x4){0.f, 0.f, 0.f, 0.f};
            accu[i][j] = (f32x4){0.f, 0.f, 0.f, 0.f};
        }

    for (int kt = 0; kt < D_DIM; kt += 32) {
        gload16(gA0 + kt, lA);
        gload16(gA1 + kt, lA + 2048);
        gload16(gB0 + kt, lBg);
        gload16(gB1 + kt, lBg + 2048);
        gload16(gU0 + kt, lBu);
        gload16(gU1 + kt, lBu + 2048);
        __syncthreads();

        bf16x8 af[4], bg[4], bu[4];
#pragma unroll
        for (int i = 0; i < 4; ++i)
            af[i] = *(const bf16x8*)(As + (wm + i * 16 + lr) * 32 + lq * 8);
#pragma unroll
        for (int j = 0; j < 4; ++j) {
            bg[j] = *(const bf16x8*)(Bg + (wn + j * 16 + lr) * 32 + lq * 8);
            bu[j] = *(const bf16x8*)(Bu + (wn + j * 16 + lr) * 32 + lq * 8);
        }
#pragma unroll
        for (int i = 0; i < 4; ++i)
#pragma unroll
            for (int j = 0; j < 4; ++j) {
                accg[i][j] = __builtin_amdgcn_mfma_f32_16x16x32_bf16(af[i], bg[j], accg[i][j], 0, 0, 0);
                accu[i][j] = __builtin_amdgcn_mfma_f32_16x16x32_bf16(af[i], bu[j], accu[i][j], 0, 0, 0);
            }
        __syncthreads();
    }

#pragma unroll
    for (int i = 0; i < 4; ++i) {
#pragma unroll
        for (int jj = 0; jj < 4; ++jj) {
            int row = wm + i * 16 + lq * 4 + jj;
            if (row < rows) {
                int slot = slots[row];
                bf16_t* hrow = h + (size_t)slot * H_DIM + (size_t)nt * 128 + wn;
#pragma unroll
                for (int j = 0; j < 4; ++j) {
                    float g = accg[i][j][jj];
                    float u = accu[i][j][jj];
                    float val = (g / (1.f + __expf(-g))) * u;
                    hrow[j * 16 + lr] = (bf16_t)val;
                }
            }
        }
    }
}

// GEMM2: contrib[slot] = (h[slot] @ Wd[e]) * comb_weight
__global__ __launch_bounds__(256, 2) void gemm2_kernel(
    const bf16_t* __restrict__ h, const bf16_t* __restrict__ wdT,
    const int* __restrict__ lists, const int* __restrict__ counts,
    const float* __restrict__ comb, bf16_t* __restrict__ contrib)
{
    const int NT = D_DIM / 128;  // 8
    const int MT = T_TOK / 128;  // 32
    int bid = blockIdx.x;
    int e = bid / (MT * NT);
    int rem = bid - e * (MT * NT);
    int mt = rem / NT;
    int nt = rem - mt * NT;
    int cnt = counts[e];
    int mbase = mt * 128;
    if (mbase >= cnt) return;
    int rows = min(128, cnt - mbase);

    __shared__ __align__(16) bf16_t As[128 * 32];
    __shared__ __align__(16) bf16_t Bs[128 * 32];
    __shared__ int slots[128];

    int tid = threadIdx.x;
    if (tid < 128) slots[tid] = (tid < rows) ? lists[e * T_TOK + mbase + tid] : 0;
    __syncthreads();

    int r0 = tid >> 2;
    int c0 = (tid & 3) * 8;
    const bf16_t* gA0 = h + (size_t)slots[r0] * H_DIM + c0;
    const bf16_t* gA1 = h + (size_t)slots[64 + r0] * H_DIM + c0;
    const bf16_t* gB0 = wdT + ((size_t)e * D_DIM + nt * 128 + r0) * H_DIM + c0;
    const bf16_t* gB1 = gB0 + (size_t)64 * H_DIM;
    bf16_t* lA = As + tid * 8;
    bf16_t* lB = Bs + tid * 8;

    int wid = tid >> 6, lane = tid & 63;
    int wm = (wid >> 1) * 64, wn = (wid & 1) * 64;
    int lr = lane & 15, lq = lane >> 4;

    f32x4 acc[4][4];
#pragma unroll
    for (int i = 0; i < 4; ++i)
#pragma unroll
        for (int j = 0; j < 4; ++j) acc[i][j] = (f32x4){0.f, 0.f, 0.f, 0.f};

    for (int kt = 0; kt < H_DIM; kt += 32) {
        gload16(gA0 + kt, lA);
        gload16(gA1 + kt, lA + 2048);
        gload16(gB0 + kt, lB);
        gload16(gB1 + kt, lB + 2048);
        __syncthreads();

        bf16x8 af[4], bf[4];
#pragma unroll
        for (int i = 0; i < 4; ++i)
            af[i] = *(const bf16x8*)(As + (wm + i * 16 + lr) * 32 + lq * 8);
#pragma unroll
        for (int j = 0; j < 4; ++j)
            bf[j] = *(const bf16x8*)(Bs + (wn + j * 16 + lr) * 32 + lq * 8);
#pragma unroll
        for (int i = 0; i < 4; ++i)
#pragma unroll
            for (int j = 0; j < 4; ++j)
                acc[i][j] = __builtin_amdgcn_mfma_f32_16x16x32_bf16(af[i], bf[j], acc[i][j], 0, 0, 0);
        __syncthreads();
    }

#pragma unroll
    for (int i = 0; i < 4; ++i) {
#pragma unroll
        for (int jj = 0; jj < 4; ++jj) {
            int row = wm + i * 16 + lq * 4 + jj;
            if (row < rows) {
                int slot = slots[row];
                float wgt = comb[(slot >> 1) * E_NUM + e];
                bf16_t* crow = contrib + (size_t)slot * D_DIM + (size_t)nt * 128 + wn;
#pragma unroll
                for (int j = 0; j < 4; ++j)
                    crow[j * 16 + lr] = (bf16_t)(acc[i][j][jj] * wgt);
            }
        }
    }
}

// out[t][d] = contrib[2t][d] + contrib[2t+1][d]
__global__ __launch_bounds__(256) void combine_kernel(
    const bf16_t* __restrict__ contrib, float* __restrict__ out)
{
    int idx = blockIdx.x * 256 + threadIdx.x;
    int t = idx >> 7;
    int d = (idx & 127) * 8;
    bf16x8 a = *(const bf16x8*)(contrib + (size_t)(2 * t) * D_DIM + d);
    bf16x8 b = *(const bf16x8*)(contrib + (size_t)(2 * t + 1) * D_DIM + d);
    float4 r0, r1;
    r0.x = (float)a[0] + (float)b[0];
    r0.y = (float)a[1] + (float)b[1];
    r0.z = (float)a[2] + (float)b[2];
    r0.w = (float)a[3] + (float)b[3];
    r1.x = (float)a[4] + (float)b[4];
    r1.y = (float)a[5] + (float)b[5];
    r1.z = (float)a[6] + (float)b[6];
    r1.w = (float)a[7] + (float)b[7];
    *(float4*)(out + (size_t)t * D_DIM + d) = r0;
    *(float4*)(out + (size_t)t * D_DIM + d + 4) = r1;
}

extern "C" void kernel_launch(void* const* d_in, const int* in_sizes, int n_in,
                              void* d_out, int out_size, void* d_ws, size_t ws_size,
                              hipStream_t stream)
{
    const float* x  = (const float*)d_in[0];
    const float* wr = (const float*)d_in[1];
    const float* wg = (const float*)d_in[2];
    const float* wu = (const float*)d_in[3];
    const float* wd = (const float*)d_in[4];
    float* out = (float*)d_out;

    char* ws = (char*)d_ws;
    int*    counts  = (int*)(ws + OFF_COUNTS);
    float*  comb    = (float*)(ws + OFF_COMB);
    int*    lists   = (int*)(ws + OFF_LISTS);
    unsigned char* pairs = (unsigned char*)(ws + OFF_PAIRS);
    bf16_t* xbf     = (bf16_t*)(ws + OFF_XBF);
    bf16_t* wgT     = (bf16_t*)(ws + OFF_WGT);
    bf16_t* wuT     = (bf16_t*)(ws + OFF_WUT);
    bf16_t* wdT     = (bf16_t*)(ws + OFF_WDT);
    bf16_t* h       = (bf16_t*)(ws + OFF_H);
    bf16_t* contrib = (bf16_t*)(ws + OFF_CONTRIB);

    // wg, wu: [E][D][H] -> [E][H][D] bf16
    transpose_cvt_kernel<<<dim3(H_DIM / 64, D_DIM / 64, E_NUM), dim3(256), 0, stream>>>(
        wg, wgT, D_DIM, H_DIM);
    transpose_cvt_kernel<<<dim3(H_DIM / 64, D_DIM / 64, E_NUM), dim3(256), 0, stream>>>(
        wu, wuT, D_DIM, H_DIM);
    // wd: [E][H][D] -> [E][D][H] bf16
    transpose_cvt_kernel<<<dim3(D_DIM / 64, H_DIM / 64, E_NUM), dim3(256), 0, stream>>>(
        wd, wdT, H_DIM, D_DIM);
    router_score_kernel<<<dim3(T_TOK / 4), dim3(256), 0, stream>>>(
        x, wr, xbf, comb, pairs);
    build_lists_kernel<<<dim3(E_NUM), dim3(256), 0, stream>>>(pairs, lists, counts);
    gemm1_kernel<<<dim3(E_NUM * (T_TOK / 128) * (H_DIM / 128)), dim3(256), 0, stream>>>(
        xbf, wgT, wuT, lists, counts, h);
    gemm2_kernel<<<dim3(E_NUM * (T_TOK / 128) * (D_DIM / 128)), dim3(256), 0, stream>>>(
        h, wdT, lists, counts, comb, contrib);
    combine_kernel<<<dim3(T_TOK * D_DIM / 8 / 256), dim3(256), 0, stream>>>(contrib, out);
}